// Round 3
// baseline (332.776 us; speedup 1.0000x reference)
//
#include <hip/hip_runtime.h>
#include <stdint.h>

// Problem constants
#define L_SEQ   900000          // 3000 words * 300 dims
#define N_WORDS 3000
#define WDIM    300
#define NB      4               // batch
#define NFPAD   320             // filters padded to 10 MFMA tiles of 32
#define NT      320             // threads per block (5 waves; wave w owns filter tiles 2w, 2w+1)
#define STRIP   3584            // positions per block = 112 steps of 32
#define STEPS   112
#define NSTAGE  (STRIP + 8)
#define NSTRIPS 252             // ceil(899968 / 3584)
#define L_MAIN  899968          // main MFMA path covers t in [0, L_MAIN); tail covers the rest

typedef __attribute__((ext_vector_type(8)))  short bf16x8;
typedef __attribute__((ext_vector_type(16))) float f32x16;

__device__ __forceinline__ unsigned bf16rne(float v) {
    unsigned b = __float_as_uint(v);
    return (b + 0x7FFFu + ((b >> 16) & 1u)) >> 16;   // bf16 round-nearest-even, as ushort
}
// order-preserving float -> uint key (atomicMax-able, works for negative values)
__device__ __forceinline__ unsigned monokey(float v) {
    unsigned u = __float_as_uint(v);
    return u ^ (unsigned)(((int)u >> 31) | 0x80000000);
}

// ---------------------------------------------------------------------------
// Fused gather + 3-term-bf16-split MFMA conv + running max + atomic key merge.
// grid (NSTRIPS+1, NB), block 320. Block bx==NSTRIPS does the exact-fp32 tail.
// ---------------------------------------------------------------------------
__global__ __launch_bounds__(NT) void conv_mfma_kernel(
    const int*   __restrict__ x,    // [4,3000]
    const float* __restrict__ emb,  // [VOCAB,300]
    const float* __restrict__ w1, const float* __restrict__ w2, const float* __restrict__ w3,
    unsigned*    __restrict__ maxkey)  // [NB][NFPAD] monotone keys, memset 0
{
    __shared__ __align__(16) unsigned       sEP[NSTAGE];     // packed {lo16,hi16} bf16 split of E
    __shared__ __align__(16) unsigned short sWhi[NFPAD * 8];
    __shared__ __align__(16) unsigned short sWlo[NFPAD * 8];

    const int tid    = threadIdx.x;
    const int b      = blockIdx.y;
    const int bx     = blockIdx.x;
    const int strip0 = bx * STRIP;

    // ---- stage E strip: gather f32, split into bf16 hi/lo, pack into u32 ----
    float vv[12];
    #pragma unroll
    for (int k = 0; k < 12; ++k) {
        int s = tid + k * NT;
        int pos = strip0 + s;
        float v = 0.f;
        if (s < NSTAGE && pos < L_SEQ) {
            int wd = pos / WDIM;
            int d  = pos - wd * WDIM;
            v = emb[x[b * N_WORDS + wd] * WDIM + d];
        }
        vv[k] = v;
    }
    #pragma unroll
    for (int k = 0; k < 12; ++k) {
        int s = tid + k * NT;
        if (s < NSTAGE) {
            float v = vv[k];
            unsigned rh = bf16rne(v);
            float lo = v - __uint_as_float(rh << 16);
            unsigned rl = bf16rne(lo);
            sEP[s] = (rl << 16) | rh;
        }
    }

    // ---- stage W split (taps padded to 8, filters padded to 320) ----
    #pragma unroll
    for (int k = 0; k < 8; ++k) {
        int idx = tid + k * NT;          // 2560 = 320*8 exactly
        int f = idx >> 3, j = idx & 7;
        float wv = 0.f;
        if (f < 100)      { if (j < 3) wv = w1[f * 3 + j]; }
        else if (f < 200) { if (j < 4) wv = w2[(f - 100) * 4 + j]; }
        else if (f < 300) { if (j < 5) wv = w3[(f - 200) * 5 + j]; }
        unsigned rh = bf16rne(wv);
        float lo = wv - __uint_as_float(rh << 16);
        sWhi[idx] = (unsigned short)rh;
        sWlo[idx] = (unsigned short)bf16rne(lo);
    }

    // ---- tail block: stage last 40 embedding values as exact f32 (aliases sEP) ----
    float* tE = (float*)sEP;
    if (bx == NSTRIPS && tid < 40) {
        int pos = L_MAIN + tid;
        float v = 0.f;
        if (pos < L_SEQ) {
            int wd = pos / WDIM;
            v = emb[x[b * N_WORDS + wd] * WDIM + (pos - wd * WDIM)];
        }
        tE[tid] = v;
    }
    __syncthreads();

    const int lane = tid & 63;
    const int col  = lane & 31;
    const int half = lane >> 5;
    const int wid  = tid >> 6;            // wave 0..4

    // ---- A fragments (loop-invariant): lanes 0-31 hold k=0..7, lanes 32-63 hold k=8..15 = 0
    bf16x8 whi0, wlo0, whi1, wlo1;
    const bf16x8 zfrag = {0,0,0,0,0,0,0,0};
    if (half == 0) {
        int f0 = (2 * wid) * 32 + col;
        int f1 = f0 + 32;
        whi0 = *(const bf16x8*)(const void*)&sWhi[f0 * 8];
        wlo0 = *(const bf16x8*)(const void*)&sWlo[f0 * 8];
        whi1 = *(const bf16x8*)(const void*)&sWhi[f1 * 8];
        wlo1 = *(const bf16x8*)(const void*)&sWlo[f1 * 8];
    } else {
        whi0 = zfrag; wlo0 = zfrag; whi1 = zfrag; wlo1 = zfrag;
    }

    int nsteps = 0;
    if (bx < NSTRIPS) {
        int rem = (L_MAIN - strip0) / 32;
        nsteps = rem < STEPS ? rem : STEPS;
    }

    f32x16 Z = {0.f,0.f,0.f,0.f,0.f,0.f,0.f,0.f,0.f,0.f,0.f,0.f,0.f,0.f,0.f,0.f};
    f32x16 rm0, rm1;
    #pragma unroll
    for (int i = 0; i < 16; ++i) { rm0[i] = -1e30f; rm1[i] = -1e30f; }

    if (nsteps > 0) {
        const unsigned* bp = sEP + col;
        unsigned p0 = bp[0], p1 = bp[1], p2 = bp[2], p3 = bp[3],
                 p4 = bp[4], p5 = bp[5], p6 = bp[6], p7 = bp[7];
        for (int s = 0; s < nsteps; ++s) {
            unsigned e0=p0,e1=p1,e2=p2,e3=p3,e4=p4,e5=p5,e6=p6,e7=p7;
            int nxt = (s + 1 < nsteps) ? (s + 1) : 0;
            const unsigned* np = sEP + col + nxt * 32;
            p0 = np[0]; p1 = np[1]; p2 = np[2]; p3 = np[3];
            p4 = np[4]; p5 = np[5]; p6 = np[6]; p7 = np[7];

            // B fragments: low halves = Ehi, high halves = Elo
            union U { unsigned u[4]; bf16x8 v; };
            U bh, bl;
            bh.u[0] = __builtin_amdgcn_perm(e1, e0, 0x05040100u);
            bl.u[0] = __builtin_amdgcn_perm(e1, e0, 0x07060302u);
            bh.u[1] = __builtin_amdgcn_perm(e3, e2, 0x05040100u);
            bl.u[1] = __builtin_amdgcn_perm(e3, e2, 0x07060302u);
            bh.u[2] = __builtin_amdgcn_perm(e5, e4, 0x05040100u);
            bl.u[2] = __builtin_amdgcn_perm(e5, e4, 0x07060302u);
            bh.u[3] = __builtin_amdgcn_perm(e7, e6, 0x05040100u);
            bl.u[3] = __builtin_amdgcn_perm(e7, e6, 0x07060302u);

            f32x16 a0 = __builtin_amdgcn_mfma_f32_32x32x16_bf16(whi0, bh.v, Z, 0, 0, 0);
            f32x16 a1 = __builtin_amdgcn_mfma_f32_32x32x16_bf16(whi1, bh.v, Z, 0, 0, 0);
            a0 = __builtin_amdgcn_mfma_f32_32x32x16_bf16(wlo0, bh.v, a0, 0, 0, 0);
            a1 = __builtin_amdgcn_mfma_f32_32x32x16_bf16(wlo1, bh.v, a1, 0, 0, 0);
            a0 = __builtin_amdgcn_mfma_f32_32x32x16_bf16(whi0, bl.v, a0, 0, 0, 0);
            a1 = __builtin_amdgcn_mfma_f32_32x32x16_bf16(whi1, bl.v, a1, 0, 0, 0);

            #pragma unroll
            for (int i = 0; i < 16; ++i) {
                rm0[i] = fmaxf(rm0[i], a0[i]);
                rm1[i] = fmaxf(rm1[i], a1[i]);
            }
        }

        // ---- reduce over cols (32 lanes within each half), then merge ----
        #pragma unroll
        for (int i = 0; i < 16; ++i) {
            float v0 = rm0[i], v1 = rm1[i];
            v0 = fmaxf(v0, __shfl_xor(v0, 1));  v1 = fmaxf(v1, __shfl_xor(v1, 1));
            v0 = fmaxf(v0, __shfl_xor(v0, 2));  v1 = fmaxf(v1, __shfl_xor(v1, 2));
            v0 = fmaxf(v0, __shfl_xor(v0, 4));  v1 = fmaxf(v1, __shfl_xor(v1, 4));
            v0 = fmaxf(v0, __shfl_xor(v0, 8));  v1 = fmaxf(v1, __shfl_xor(v1, 8));
            v0 = fmaxf(v0, __shfl_xor(v0, 16)); v1 = fmaxf(v1, __shfl_xor(v1, 16));
            if (col == 0) {
                int row = (i & 3) + 8 * (i >> 2) + 4 * half;   // C/D layout, m74/m101
                atomicMax(&maxkey[b * NFPAD + (2 * wid) * 32 + row], monokey(v0));
                atomicMax(&maxkey[b * NFPAD + (2 * wid + 1) * 32 + row], monokey(v1));
            }
        }
    }

    // ---- exact fp32 tail: t in [L_MAIN, L_SEQ-K] (valid-t depends on K) ----
    if (bx == NSTRIPS && tid < 300) {
        const float* tEf = (const float*)sEP;
        int f = tid, K;
        const float* wp;
        if (f < 100)      { K = 3; wp = w1 + f * 3; }
        else if (f < 200) { K = 4; wp = w2 + (f - 100) * 4; }
        else              { K = 5; wp = w3 + (f - 200) * 5; }
        float wk0 = wp[0], wk1 = wp[1], wk2 = (K > 2) ? wp[2] : 0.f;
        float wk3 = (K > 3) ? wp[3] : 0.f, wk4 = (K > 4) ? wp[4] : 0.f;
        float m = -1e30f;
        int tmax = L_SEQ - K;
        for (int t = L_MAIN; t <= tmax; ++t) {
            int o = t - L_MAIN;
            float y = wk0 * tEf[o] + wk1 * tEf[o + 1] + wk2 * tEf[o + 2]
                    + wk3 * tEf[o + 3] + wk4 * tEf[o + 4];
            m = fmaxf(m, y);
        }
        atomicMax(&maxkey[b * NFPAD + f], monokey(m));
    }
}

// ---------------------------------------------------------------------------
// FC heads: decode keys -> relu(max + bias) -> 5 small matvecs. grid(NB), 128 thr
// ---------------------------------------------------------------------------
__global__ __launch_bounds__(128) void fc_kernel(
    const unsigned* __restrict__ maxkey,
    const float* __restrict__ cb1, const float* __restrict__ cb2, const float* __restrict__ cb3,
    const float* __restrict__ fw1, const float* __restrict__ fb1,
    const float* __restrict__ fw2, const float* __restrict__ fb2,
    const float* __restrict__ fw3, const float* __restrict__ fb3,
    const float* __restrict__ fw4, const float* __restrict__ fb4,
    const float* __restrict__ fw5, const float* __restrict__ fb5,
    float* __restrict__ out)   // [360] flat: 136 + 16 + 12 + 176 + 20
{
    __shared__ __align__(16) float feats[WDIM];
    const int b   = blockIdx.x;
    const int tid = threadIdx.x;

    for (int f = tid; f < WDIM; f += 128) {
        unsigned k = maxkey[b * NFPAD + f];
        unsigned u = (k & 0x80000000u) ? (k ^ 0x80000000u) : ~k;
        float y = __uint_as_float(u);
        float bias = (f < 100) ? cb1[f] : (f < 200) ? cb2[f - 100] : cb3[f - 200];
        feats[f] = fmaxf(0.f, y + bias);
    }
    __syncthreads();

    if (tid >= 90) return;
    const float* Wh; const float* Bh; int dim, off, j;
    int n = tid;
    if      (n < 34) { Wh = fw1; Bh = fb1; dim = 34; off = 0;   j = n;      }
    else if (n < 38) { Wh = fw2; Bh = fb2; dim = 4;  off = 136; j = n - 34; }
    else if (n < 41) { Wh = fw3; Bh = fb3; dim = 3;  off = 152; j = n - 38; }
    else if (n < 85) { Wh = fw4; Bh = fb4; dim = 44; off = 164; j = n - 41; }
    else             { Wh = fw5; Bh = fb5; dim = 5;  off = 340; j = n - 85; }

    float acc = Bh[j];
    const float* wr = Wh + j * WDIM;
    #pragma unroll 5
    for (int k = 0; k < WDIM; k += 4) {
        float4 wv = *reinterpret_cast<const float4*>(wr + k);
        acc = fmaf(wv.x, feats[k + 0], acc);
        acc = fmaf(wv.y, feats[k + 1], acc);
        acc = fmaf(wv.z, feats[k + 2], acc);
        acc = fmaf(wv.w, feats[k + 3], acc);
    }
    out[off + b * dim + j] = acc;
}

// ---------------------------------------------------------------------------
extern "C" void kernel_launch(void* const* d_in, const int* in_sizes, int n_in,
                              void* d_out, int out_size, void* d_ws, size_t ws_size,
                              hipStream_t stream) {
    const int*   x    = (const int*)  d_in[0];
    const float* emb  = (const float*)d_in[1];
    const float* w1   = (const float*)d_in[2];
    const float* b1   = (const float*)d_in[3];
    const float* w2   = (const float*)d_in[4];
    const float* b2   = (const float*)d_in[5];
    const float* w3   = (const float*)d_in[6];
    const float* b3   = (const float*)d_in[7];
    const float* fw1  = (const float*)d_in[8];
    const float* fb1  = (const float*)d_in[9];
    const float* fw2  = (const float*)d_in[10];
    const float* fb2  = (const float*)d_in[11];
    const float* fw3  = (const float*)d_in[12];
    const float* fb3  = (const float*)d_in[13];
    const float* fw4  = (const float*)d_in[14];
    const float* fb4  = (const float*)d_in[15];
    const float* fw5  = (const float*)d_in[16];
    const float* fb5  = (const float*)d_in[17];
    float*    out    = (float*)d_out;
    unsigned* maxkey = (unsigned*)d_ws;      // [4*320] monotone keys

    hipMemsetAsync(maxkey, 0, NB * NFPAD * sizeof(unsigned), stream);

    dim3 grid(NSTRIPS + 1, NB);
    conv_mfma_kernel<<<grid, NT, 0, stream>>>(x, emb, w1, w2, w3, maxkey);

    fc_kernel<<<NB, 128, 0, stream>>>(maxkey, b1, b2, b3,
                                      fw1, fb1, fw2, fb2, fw3, fb3,
                                      fw4, fb4, fw5, fb5, out);
}

// Round 5
// 263.010 us; speedup vs baseline: 1.2653x; 1.2653x over previous
//
#include <hip/hip_runtime.h>
#include <stdint.h>

// Problem constants
#define L_SEQ   900000          // 3000 words * 300 dims
#define N_WORDS 3000
#define WDIM    300
#define NB      4               // batch
#define NFPAD   320             // filters padded to 20 MFMA tiles of 16
#define NT      256             // threads per block (4 waves; wave w owns tiles 5w..5w+4)
#define STRIP   3072            // positions per block = 192 steps of 16
#define STEPS   192
#define NSTG    3088            // staged raw E per strip (STRIP + 16 pad)
#define NSTRIPS 293             // ceil(899968/3072)
#define L_MAIN  899968          // main MFMA path covers t in [0, L_MAIN); tail covers the rest

typedef __attribute__((ext_vector_type(8))) short bf16x8;
typedef __attribute__((ext_vector_type(4))) float f32x4;

__device__ __forceinline__ unsigned bf16rne(float v) {
    unsigned b = __float_as_uint(v);
    return (b + 0x7FFFu + ((b >> 16) & 1u)) >> 16;   // bf16 RNE, as ushort
}
// order-preserving float -> uint key (atomicMax-able, handles negatives)
__device__ __forceinline__ unsigned monokey(float v) {
    unsigned u = __float_as_uint(v);
    return u ^ (unsigned)(((int)u >> 31) | 0x80000000);
}

// ---------------------------------------------------------------------------
// Fused gather + full-split-in-K MFMA conv + running max + atomic key merge.
// One mfma_f32_16x16x32_bf16 per (16 filters x 16 positions) step:
//   A quarters (k-groups) = {Whi, Wlo, Whi, Wlo}
//   B quarters            = {Ehi, Ehi, Elo, Elo}
//   => D = sum_j (Whi+Wlo)_j * (Ehi+Elo)_j  (full split product, no chain)
// grid (NSTRIPS+1, NB), block 256. Block bx==NSTRIPS does the exact-fp32 tail.
// ---------------------------------------------------------------------------
__global__ __launch_bounds__(NT, 2) void conv_mfma_kernel(
    const int*   __restrict__ x,    // [4,3000]
    const float* __restrict__ emb,  // [VOCAB,300]
    const float* __restrict__ w1, const float* __restrict__ w2, const float* __restrict__ w3,
    unsigned*    __restrict__ maxkey)  // [NB][NFPAD] monotone keys, memset 0
{
    // union LDS: phase-W = ushort sW[2][2560] (10240 B);
    //            phase-E = u32 uE[2][NSTG] (24704 B); tail = float tE[48]
    __shared__ __align__(16) unsigned buf[2 * NSTG];

    const int tid = threadIdx.x;
    const int b   = blockIdx.y;
    const int bx  = blockIdx.x;

    if (bx == NSTRIPS) {
        // ---------------- exact fp32 tail: t in [L_MAIN, L_SEQ-K] ----------------
        float* tE = (float*)buf;
        if (tid < 48) {
            int pos = L_MAIN + tid;
            float v = 0.f;
            if (pos < L_SEQ) {
                int wd = pos / WDIM;
                v = emb[x[b * N_WORDS + wd] * WDIM + (pos - wd * WDIM)];
            }
            tE[tid] = v;
        }
        __syncthreads();
        for (int f = tid; f < 300; f += NT) {
            int K; const float* wp;
            if (f < 100)      { K = 3; wp = w1 + f * 3; }
            else if (f < 200) { K = 4; wp = w2 + (f - 100) * 4; }
            else              { K = 5; wp = w3 + (f - 200) * 5; }
            float wk0 = wp[0], wk1 = wp[1], wk2 = (K > 2) ? wp[2] : 0.f;
            float wk3 = (K > 3) ? wp[3] : 0.f, wk4 = (K > 4) ? wp[4] : 0.f;
            float m = -1e30f;
            int tmax = L_SEQ - K;
            for (int t = L_MAIN; t <= tmax; ++t) {
                int o = t - L_MAIN;
                float y = wk0 * tE[o] + wk1 * tE[o + 1] + wk2 * tE[o + 2]
                        + wk3 * tE[o + 3] + wk4 * tE[o + 4];
                m = fmaxf(m, y);
            }
            atomicMax(&maxkey[b * NFPAD + f], monokey(m));
        }
        return;
    }

    const int strip0 = bx * STRIP;

    // ---- gather raw E into regs (13 per thread); long-latency loads issue early ----
    float vv[13];
    #pragma unroll
    for (int k = 0; k < 13; ++k) {
        int s = tid + k * NT;
        int pos = strip0 + s;
        float v = 0.f;
        if (s < NSTG && pos < L_SEQ) {
            int wd = pos / WDIM;
            v = emb[x[b * N_WORDS + wd] * WDIM + (pos - wd * WDIM)];
        }
        vv[k] = v;
    }

    // ---- stage W split into LDS: sW[part][f*8+j], taps padded to 8 ----
    unsigned short* sW = (unsigned short*)buf;   // part*2560 + f*8 + j
    #pragma unroll
    for (int k = 0; k < 10; ++k) {
        int idx = tid + k * NT;                  // 2560 = 256*10 exactly
        int f = idx >> 3, j = idx & 7;
        float wv = 0.f;
        if (f < 100)      { if (j < 3) wv = w1[f * 3 + j]; }
        else if (f < 200) { if (j < 4) wv = w2[(f - 100) * 4 + j]; }
        else if (f < 300) { if (j < 5) wv = w3[(f - 200) * 5 + j]; }
        unsigned rh = bf16rne(wv);
        float lo = wv - __uint_as_float(rh << 16);
        sW[idx]        = (unsigned short)rh;
        sW[2560 + idx] = (unsigned short)bf16rne(lo);
    }
    __syncthreads();

    // ---- A fragments: 5 tiles/wave; lane quarter q: part = q&1 (hi,lo,hi,lo) ----
    const int lane = tid & 63;
    const int wid  = tid >> 6;           // wave 0..3
    const int col  = lane & 15;
    const int q    = lane >> 4;          // k-group 0..3
    const int part = q & 1;
    bf16x8 aw[5];
    #pragma unroll
    for (int t = 0; t < 5; ++t) {
        int f = (5 * wid + t) * 16 + col;
        aw[t] = *(const bf16x8*)(const void*)&sW[part * 2560 + f * 8];
    }
    __syncthreads();                     // sW reads done; buf about to be reused

    // ---- E raw -> LDS, grab neighbor, write packed pair arrays ----
    float* rawE = (float*)buf;
    #pragma unroll
    for (int k = 0; k < 13; ++k) {
        int s = tid + k * NT;
        if (s < NSTG) rawE[s] = vv[k];
    }
    __syncthreads();
    float nv[13];
    #pragma unroll
    for (int k = 0; k < 13; ++k) {
        int s = tid + k * NT;
        nv[k] = (s + 1 < NSTG) ? rawE[s + 1] : 0.f;
    }
    __syncthreads();
    // uE[0][p] = {hi[p], hi[p+1]}  (overwrites rawE — all raw reads done above)
    // uE[1][p] = {lo[p], lo[p+1]}
    #pragma unroll
    for (int k = 0; k < 13; ++k) {
        int s = tid + k * NT;
        if (s < NSTG) {
            float a = vv[k], c = nv[k];
            unsigned ah = bf16rne(a), ch = bf16rne(c);
            float al = a - __uint_as_float(ah << 16);
            float cl = c - __uint_as_float(ch << 16);
            buf[s]        = ah | (ch << 16);
            buf[NSTG + s] = bf16rne(al) | (bf16rne(cl) << 16);
        }
    }
    __syncthreads();

    // ---- main loop: 1 MFMA per tile per 16-position step ----
    int nsteps = (L_MAIN - strip0) / 16;
    if (nsteps > STEPS) nsteps = STEPS;

    const f32x4 Z = {0.f, 0.f, 0.f, 0.f};
    f32x4 rm[5];
    #pragma unroll
    for (int t = 0; t < 5; ++t) { rm[t][0] = rm[t][1] = rm[t][2] = rm[t][3] = -1e30f; }

    // B source: lanes 0-31 read hi array, 32-63 read lo array (quarters {hi,hi,lo,lo})
    const unsigned* uEh = buf + ((lane >> 5) ? NSTG : 0) + col;
    for (int s = 0; s < nsteps; ++s) {
        const unsigned* p = uEh + s * 16;
        union { unsigned u[4]; bf16x8 v; } B;
        B.u[0] = p[0]; B.u[1] = p[2]; B.u[2] = p[4]; B.u[3] = p[6];
        #pragma unroll
        for (int t = 0; t < 5; ++t) {
            f32x4 d = __builtin_amdgcn_mfma_f32_16x16x32_bf16(aw[t], B.v, Z, 0, 0, 0);
            rm[t][0] = fmaxf(rm[t][0], d[0]);
            rm[t][1] = fmaxf(rm[t][1], d[1]);
            rm[t][2] = fmaxf(rm[t][2], d[2]);
            rm[t][3] = fmaxf(rm[t][3], d[3]);
        }
    }

    // ---- reduce over 16 position-cols, then atomic merge (f_local = q*4 + r) ----
    #pragma unroll
    for (int t = 0; t < 5; ++t) {
        #pragma unroll
        for (int r = 0; r < 4; ++r) {
            float v = rm[t][r];
            v = fmaxf(v, __shfl_xor(v, 1));
            v = fmaxf(v, __shfl_xor(v, 2));
            v = fmaxf(v, __shfl_xor(v, 4));
            v = fmaxf(v, __shfl_xor(v, 8));
            if (col == 0) {
                int f = (5 * wid + t) * 16 + q * 4 + r;   // C/D: row=(lane>>4)*4+reg
                atomicMax(&maxkey[b * NFPAD + f], monokey(v));
            }
        }
    }
}

// ---------------------------------------------------------------------------
// FC heads: decode keys -> relu(max + bias) -> 5 small matvecs. grid(NB), 128 thr
// ---------------------------------------------------------------------------
__global__ __launch_bounds__(128) void fc_kernel(
    const unsigned* __restrict__ maxkey,
    const float* __restrict__ cb1, const float* __restrict__ cb2, const float* __restrict__ cb3,
    const float* __restrict__ fw1, const float* __restrict__ fb1,
    const float* __restrict__ fw2, const float* __restrict__ fb2,
    const float* __restrict__ fw3, const float* __restrict__ fb3,
    const float* __restrict__ fw4, const float* __restrict__ fb4,
    const float* __restrict__ fw5, const float* __restrict__ fb5,
    float* __restrict__ out)   // [360] flat: 136 + 16 + 12 + 176 + 20
{
    __shared__ __align__(16) float feats[WDIM];
    const int b   = blockIdx.x;
    const int tid = threadIdx.x;

    for (int f = tid; f < WDIM; f += 128) {
        unsigned k = maxkey[b * NFPAD + f];
        unsigned u = (k & 0x80000000u) ? (k ^ 0x80000000u) : ~k;
        float y = __uint_as_float(u);
        float bias = (f < 100) ? cb1[f] : (f < 200) ? cb2[f - 100] : cb3[f - 200];
        feats[f] = fmaxf(0.f, y + bias);
    }
    __syncthreads();

    if (tid >= 90) return;
    const float* Wh; const float* Bh; int dim, off, j;
    int n = tid;
    if      (n < 34) { Wh = fw1; Bh = fb1; dim = 34; off = 0;   j = n;      }
    else if (n < 38) { Wh = fw2; Bh = fb2; dim = 4;  off = 136; j = n - 34; }
    else if (n < 41) { Wh = fw3; Bh = fb3; dim = 3;  off = 152; j = n - 38; }
    else if (n < 85) { Wh = fw4; Bh = fb4; dim = 44; off = 164; j = n - 41; }
    else             { Wh = fw5; Bh = fb5; dim = 5;  off = 340; j = n - 85; }

    float acc = Bh[j];
    const float* wr = Wh + j * WDIM;
    #pragma unroll 5
    for (int k = 0; k < WDIM; k += 4) {
        float4 wv = *reinterpret_cast<const float4*>(wr + k);
        acc = fmaf(wv.x, feats[k + 0], acc);
        acc = fmaf(wv.y, feats[k + 1], acc);
        acc = fmaf(wv.z, feats[k + 2], acc);
        acc = fmaf(wv.w, feats[k + 3], acc);
    }
    out[off + b * dim + j] = acc;
}

// ---------------------------------------------------------------------------
extern "C" void kernel_launch(void* const* d_in, const int* in_sizes, int n_in,
                              void* d_out, int out_size, void* d_ws, size_t ws_size,
                              hipStream_t stream) {
    const int*   x    = (const int*)  d_in[0];
    const float* emb  = (const float*)d_in[1];
    const float* w1   = (const float*)d_in[2];
    const float* b1   = (const float*)d_in[3];
    const float* w2   = (const float*)d_in[4];
    const float* b2   = (const float*)d_in[5];
    const float* w3   = (const float*)d_in[6];
    const float* b3   = (const float*)d_in[7];
    const float* fw1  = (const float*)d_in[8];
    const float* fb1  = (const float*)d_in[9];
    const float* fw2  = (const float*)d_in[10];
    const float* fb2  = (const float*)d_in[11];
    const float* fw3  = (const float*)d_in[12];
    const float* fb3  = (const float*)d_in[13];
    const float* fw4  = (const float*)d_in[14];
    const float* fb4  = (const float*)d_in[15];
    const float* fw5  = (const float*)d_in[16];
    const float* fb5  = (const float*)d_in[17];
    float*    out    = (float*)d_out;
    unsigned* maxkey = (unsigned*)d_ws;      // [4*320] monotone keys

    hipMemsetAsync(maxkey, 0, NB * NFPAD * sizeof(unsigned), stream);

    dim3 grid(NSTRIPS + 1, NB);
    conv_mfma_kernel<<<grid, NT, 0, stream>>>(x, emb, w1, w2, w3, maxkey);

    fc_kernel<<<NB, 128, 0, stream>>>(maxkey, b1, b2, b3,
                                      fw1, fb1, fw2, fb2, fw3, fb3,
                                      fw4, fb4, fw5, fb5, out);
}

// Round 6
// 207.847 us; speedup vs baseline: 1.6011x; 1.2654x over previous
//
#include <hip/hip_runtime.h>
#include <stdint.h>

// Problem constants
#define L_SEQ   900000          // 3000 words * 300 dims
#define N_WORDS 3000
#define WDIM    300
#define NB      4               // batch
#define NFPAD   320             // filters padded to 20 MFMA tiles of 16
#define NT      256             // threads per block (4 waves; wave w owns tiles 5w..5w+4)
#define STRIP   3072            // positions per block = 192 steps of 16
#define STEPS   192
#define NSTG    3088            // staged raw E per strip (STRIP + 16 pad)
#define NSTRIPS 293             // ceil(899968/3072)
#define L_MAIN  899968          // main MFMA path covers t in [0, L_MAIN); tail covers the rest

typedef __attribute__((ext_vector_type(8))) short    bf16x8;
typedef __attribute__((ext_vector_type(4))) float    f32x4;
typedef __attribute__((ext_vector_type(4))) unsigned u32x4v;

__device__ __forceinline__ unsigned bf16rne(float v) {
    unsigned b = __float_as_uint(v);
    return (b + 0x7FFFu + ((b >> 16) & 1u)) >> 16;   // bf16 RNE, as ushort
}
// order-preserving float -> uint key (atomicMax-able, handles negatives)
__device__ __forceinline__ unsigned monokey(float v) {
    unsigned u = __float_as_uint(v);
    return u ^ (unsigned)(((int)u >> 31) | 0x80000000);
}
// pack two f32 -> {bf16(a) lo16, bf16(b) hi16} (RNE) — no builtin on gfx950
__device__ __forceinline__ unsigned cvt_pk_bf16(float a, float b) {
    unsigned r;
    asm("v_cvt_pk_bf16_f32 %0, %1, %2" : "=v"(r) : "v"(a), "v"(b));
    return r;
}

// ---------------------------------------------------------------------------
// Fused gather + full-split-in-K MFMA conv + running max + atomic key merge.
// One mfma_f32_16x16x32_bf16 per (16 filters x 16 positions) step:
//   A quarters (k-groups) = {Whi, Wlo, Whi, Wlo}
//   B quarters            = {Ehi, Ehi, Elo, Elo}
//   => D = sum_j (Whi+Wlo)_j * (Ehi+Elo)_j  (full split product, no chain)
// E split: hi = trunc16(v), lo = bf16rne(v - hi)  (same 2^-17 error class)
// grid (NSTRIPS+1, NB), block 256. Block bx==NSTRIPS does the exact-fp32 tail.
// ---------------------------------------------------------------------------
__global__ __launch_bounds__(NT) __attribute__((amdgpu_waves_per_eu(2, 4)))
void conv_mfma_kernel(
    const int*   __restrict__ x,    // [4,3000]
    const float* __restrict__ emb,  // [VOCAB,300]
    const float* __restrict__ w1, const float* __restrict__ w2, const float* __restrict__ w3,
    unsigned*    __restrict__ maxkey)  // [NB][NFPAD] monotone keys, memset 0
{
    // union LDS: phase-W = ushort sW[2][2560]; phase-E raw = float rawE[NSTG];
    //            phase-E packed = u32 uE[2][NSTG]; tail = float tE[48]
    __shared__ __align__(16) unsigned buf[2 * NSTG];

    const int tid = threadIdx.x;
    const int b   = blockIdx.y;
    const int bx  = blockIdx.x;

    if (bx == NSTRIPS) {
        // ---------------- exact fp32 tail: t in [L_MAIN, L_SEQ-K] ----------------
        float* tE = (float*)buf;
        if (tid < 48) {
            int pos = L_MAIN + tid;
            float v = 0.f;
            if (pos < L_SEQ) {
                int wd = pos / WDIM;
                v = emb[x[b * N_WORDS + wd] * WDIM + (pos - wd * WDIM)];
            }
            tE[tid] = v;
        }
        __syncthreads();
        for (int f = tid; f < 300; f += NT) {
            int K; const float* wp;
            if (f < 100)      { K = 3; wp = w1 + f * 3; }
            else if (f < 200) { K = 4; wp = w2 + (f - 100) * 4; }
            else              { K = 5; wp = w3 + (f - 200) * 5; }
            float wk0 = wp[0], wk1 = wp[1], wk2 = (K > 2) ? wp[2] : 0.f;
            float wk3 = (K > 3) ? wp[3] : 0.f, wk4 = (K > 4) ? wp[4] : 0.f;
            float m = -1e30f;
            int tmax = L_SEQ - K;
            for (int t = L_MAIN; t <= tmax; ++t) {
                int o = t - L_MAIN;
                float y = wk0 * tE[o] + wk1 * tE[o + 1] + wk2 * tE[o + 2]
                        + wk3 * tE[o + 3] + wk4 * tE[o + 4];
                m = fmaxf(m, y);
            }
            atomicMax(&maxkey[b * NFPAD + f], monokey(m));
        }
        return;
    }

    const int strip0 = bx * STRIP;

    // ---- gather raw E into regs (13 per thread); long-latency loads issue early ----
    float vv[13];
    #pragma unroll
    for (int k = 0; k < 13; ++k) {
        int s = tid + k * NT;
        int pos = strip0 + s;
        float v = 0.f;
        if (s < NSTG && pos < L_SEQ) {
            int wd = pos / WDIM;
            v = emb[x[b * N_WORDS + wd] * WDIM + (pos - wd * WDIM)];
        }
        vv[k] = v;
    }

    // ---- stage W split into LDS: sW[part][f*8+j], taps padded to 8 ----
    unsigned short* sW = (unsigned short*)buf;   // part*2560 + f*8 + j
    #pragma unroll
    for (int k = 0; k < 10; ++k) {
        int idx = tid + k * NT;                  // 2560 = 256*10 exactly
        int f = idx >> 3, j = idx & 7;
        float wv = 0.f;
        if (f < 100)      { if (j < 3) wv = w1[f * 3 + j]; }
        else if (f < 200) { if (j < 4) wv = w2[(f - 100) * 4 + j]; }
        else if (f < 300) { if (j < 5) wv = w3[(f - 200) * 5 + j]; }
        unsigned rh = bf16rne(wv);
        float lo = wv - __uint_as_float(rh << 16);
        sW[idx]        = (unsigned short)rh;
        sW[2560 + idx] = (unsigned short)bf16rne(lo);
    }
    __syncthreads();

    // ---- A fragments: 5 tiles/wave; lane quarter q: part = q&1 (hi,lo,hi,lo) ----
    const int lane = tid & 63;
    const int wid  = tid >> 6;           // wave 0..3
    const int col  = lane & 15;
    const int q    = lane >> 4;          // k-group 0..3
    const int part = q & 1;
    bf16x8 aw0, aw1, aw2, aw3, aw4;
    {
        int f = (5 * wid) * 16 + col;
        const unsigned short* wbase = &sW[part * 2560 + f * 8];
        aw0 = *(const bf16x8*)(const void*)(wbase + 0 * 128);
        aw1 = *(const bf16x8*)(const void*)(wbase + 1 * 128);
        aw2 = *(const bf16x8*)(const void*)(wbase + 2 * 128);
        aw3 = *(const bf16x8*)(const void*)(wbase + 3 * 128);
        aw4 = *(const bf16x8*)(const void*)(wbase + 4 * 128);
    }
    __syncthreads();                     // sW reads done; buf about to be reused

    // ---- E raw -> LDS, grab neighbor, write packed pair arrays ----
    float* rawE = (float*)buf;
    #pragma unroll
    for (int k = 0; k < 13; ++k) {
        int s = tid + k * NT;
        if (s < NSTG) rawE[s] = vv[k];
    }
    __syncthreads();
    float nv[13];
    #pragma unroll
    for (int k = 0; k < 13; ++k) {
        int s = tid + k * NT;
        nv[k] = (s + 1 < NSTG) ? rawE[s + 1] : 0.f;
    }
    __syncthreads();
    // uE[0][p] = {hi(v[p]), hi(v[p+1])}   hi = trunc16 (1 v_perm for the pair)
    // uE[1][p] = {lo(v[p]), lo(v[p+1])}   lo = RNE(v - hi) (1 v_cvt_pk_bf16_f32)
    #pragma unroll
    for (int k = 0; k < 13; ++k) {
        int s = tid + k * NT;
        if (s < NSTG) {
            float v0 = vv[k], v1 = nv[k];
            unsigned u0 = __float_as_uint(v0), u1 = __float_as_uint(v1);
            float l0 = v0 - __uint_as_float(u0 & 0xFFFF0000u);
            float l1 = v1 - __uint_as_float(u1 & 0xFFFF0000u);
            buf[s]        = __builtin_amdgcn_perm(u1, u0, 0x07060302u); // {hi0, hi1}
            buf[NSTG + s] = cvt_pk_bf16(l0, l1);                        // {lo0, lo1}
        }
    }
    __syncthreads();

    // ---- main loop: 1 MFMA per tile per 16-position step, unrolled x2 ----
    int nsteps = (L_MAIN - strip0) / 16;     // 192 or 184 — always even
    if (nsteps > STEPS) nsteps = STEPS;

    const f32x4 Z = {0.f, 0.f, 0.f, 0.f};
    f32x4 rm0 = {-1e30f,-1e30f,-1e30f,-1e30f}, rm1 = rm0, rm2 = rm0, rm3 = rm0, rm4 = rm0;

    // B source: lanes 0-31 read hi array, 32-63 read lo array (quarters {hi,hi,lo,lo})
    const unsigned* bp = buf + ((lane >> 5) ? NSTG : 0) + col;
    for (int s = 0; s < nsteps; s += 2) {
        u32x4v ba = {bp[0],  bp[2],  bp[4],  bp[6]};
        u32x4v bb = {bp[16], bp[18], bp[20], bp[22]};
        bf16x8 Bav = __builtin_bit_cast(bf16x8, ba);
        bf16x8 Bbv = __builtin_bit_cast(bf16x8, bb);
        f32x4 d0 = __builtin_amdgcn_mfma_f32_16x16x32_bf16(aw0, Bav, Z, 0, 0, 0);
        f32x4 d1 = __builtin_amdgcn_mfma_f32_16x16x32_bf16(aw1, Bav, Z, 0, 0, 0);
        f32x4 d2 = __builtin_amdgcn_mfma_f32_16x16x32_bf16(aw2, Bav, Z, 0, 0, 0);
        f32x4 d3 = __builtin_amdgcn_mfma_f32_16x16x32_bf16(aw3, Bav, Z, 0, 0, 0);
        f32x4 d4 = __builtin_amdgcn_mfma_f32_16x16x32_bf16(aw4, Bav, Z, 0, 0, 0);
        #pragma unroll
        for (int r = 0; r < 4; ++r) {
            rm0[r] = fmaxf(rm0[r], d0[r]);
            rm1[r] = fmaxf(rm1[r], d1[r]);
            rm2[r] = fmaxf(rm2[r], d2[r]);
            rm3[r] = fmaxf(rm3[r], d3[r]);
            rm4[r] = fmaxf(rm4[r], d4[r]);
        }
        d0 = __builtin_amdgcn_mfma_f32_16x16x32_bf16(aw0, Bbv, Z, 0, 0, 0);
        d1 = __builtin_amdgcn_mfma_f32_16x16x32_bf16(aw1, Bbv, Z, 0, 0, 0);
        d2 = __builtin_amdgcn_mfma_f32_16x16x32_bf16(aw2, Bbv, Z, 0, 0, 0);
        d3 = __builtin_amdgcn_mfma_f32_16x16x32_bf16(aw3, Bbv, Z, 0, 0, 0);
        d4 = __builtin_amdgcn_mfma_f32_16x16x32_bf16(aw4, Bbv, Z, 0, 0, 0);
        #pragma unroll
        for (int r = 0; r < 4; ++r) {
            rm0[r] = fmaxf(rm0[r], d0[r]);
            rm1[r] = fmaxf(rm1[r], d1[r]);
            rm2[r] = fmaxf(rm2[r], d2[r]);
            rm3[r] = fmaxf(rm3[r], d3[r]);
            rm4[r] = fmaxf(rm4[r], d4[r]);
        }
        bp += 32;
    }

    // ---- reduce over 16 position-cols, then atomic merge (f_local = q*4 + r) ----
    f32x4 rms[5] = {rm0, rm1, rm2, rm3, rm4};
    #pragma unroll
    for (int t = 0; t < 5; ++t) {
        #pragma unroll
        for (int r = 0; r < 4; ++r) {
            float v = rms[t][r];
            v = fmaxf(v, __shfl_xor(v, 1));
            v = fmaxf(v, __shfl_xor(v, 2));
            v = fmaxf(v, __shfl_xor(v, 4));
            v = fmaxf(v, __shfl_xor(v, 8));
            if (col == 0) {
                int f = (5 * wid + t) * 16 + q * 4 + r;   // C/D: row=(lane>>4)*4+reg
                atomicMax(&maxkey[b * NFPAD + f], monokey(v));
            }
        }
    }
}

// ---------------------------------------------------------------------------
// FC heads: decode keys -> relu(max + bias) -> 5 small matvecs. grid(NB), 128 thr
// ---------------------------------------------------------------------------
__global__ __launch_bounds__(128) void fc_kernel(
    const unsigned* __restrict__ maxkey,
    const float* __restrict__ cb1, const float* __restrict__ cb2, const float* __restrict__ cb3,
    const float* __restrict__ fw1, const float* __restrict__ fb1,
    const float* __restrict__ fw2, const float* __restrict__ fb2,
    const float* __restrict__ fw3, const float* __restrict__ fb3,
    const float* __restrict__ fw4, const float* __restrict__ fb4,
    const float* __restrict__ fw5, const float* __restrict__ fb5,
    float* __restrict__ out)   // [360] flat: 136 + 16 + 12 + 176 + 20
{
    __shared__ __align__(16) float feats[WDIM];
    const int b   = blockIdx.x;
    const int tid = threadIdx.x;

    for (int f = tid; f < WDIM; f += 128) {
        unsigned k = maxkey[b * NFPAD + f];
        unsigned u = (k & 0x80000000u) ? (k ^ 0x80000000u) : ~k;
        float y = __uint_as_float(u);
        float bias = (f < 100) ? cb1[f] : (f < 200) ? cb2[f - 100] : cb3[f - 200];
        feats[f] = fmaxf(0.f, y + bias);
    }
    __syncthreads();

    if (tid >= 90) return;
    const float* Wh; const float* Bh; int dim, off, j;
    int n = tid;
    if      (n < 34) { Wh = fw1; Bh = fb1; dim = 34; off = 0;   j = n;      }
    else if (n < 38) { Wh = fw2; Bh = fb2; dim = 4;  off = 136; j = n - 34; }
    else if (n < 41) { Wh = fw3; Bh = fb3; dim = 3;  off = 152; j = n - 38; }
    else if (n < 85) { Wh = fw4; Bh = fb4; dim = 44; off = 164; j = n - 41; }
    else             { Wh = fw5; Bh = fb5; dim = 5;  off = 340; j = n - 85; }

    float acc = Bh[j];
    const float* wr = Wh + j * WDIM;
    #pragma unroll 5
    for (int k = 0; k < WDIM; k += 4) {
        float4 wv = *reinterpret_cast<const float4*>(wr + k);
        acc = fmaf(wv.x, feats[k + 0], acc);
        acc = fmaf(wv.y, feats[k + 1], acc);
        acc = fmaf(wv.z, feats[k + 2], acc);
        acc = fmaf(wv.w, feats[k + 3], acc);
    }
    out[off + b * dim + j] = acc;
}

// ---------------------------------------------------------------------------
extern "C" void kernel_launch(void* const* d_in, const int* in_sizes, int n_in,
                              void* d_out, int out_size, void* d_ws, size_t ws_size,
                              hipStream_t stream) {
    const int*   x    = (const int*)  d_in[0];
    const float* emb  = (const float*)d_in[1];
    const float* w1   = (const float*)d_in[2];
    const float* b1   = (const float*)d_in[3];
    const float* w2   = (const float*)d_in[4];
    const float* b2   = (const float*)d_in[5];
    const float* w3   = (const float*)d_in[6];
    const float* b3   = (const float*)d_in[7];
    const float* fw1  = (const float*)d_in[8];
    const float* fb1  = (const float*)d_in[9];
    const float* fw2  = (const float*)d_in[10];
    const float* fb2  = (const float*)d_in[11];
    const float* fw3  = (const float*)d_in[12];
    const float* fb3  = (const float*)d_in[13];
    const float* fw4  = (const float*)d_in[14];
    const float* fb4  = (const float*)d_in[15];
    const float* fw5  = (const float*)d_in[16];
    const float* fb5  = (const float*)d_in[17];
    float*    out    = (float*)d_out;
    unsigned* maxkey = (unsigned*)d_ws;      // [4*320] monotone keys

    hipMemsetAsync(maxkey, 0, NB * NFPAD * sizeof(unsigned), stream);

    dim3 grid(NSTRIPS + 1, NB);
    conv_mfma_kernel<<<grid, NT, 0, stream>>>(x, emb, w1, w2, w3, maxkey);

    fc_kernel<<<NB, 128, 0, stream>>>(maxkey, b1, b2, b3,
                                      fw1, fb1, fw2, fb2, fw3, fb3,
                                      fw4, fb4, fw5, fb5, out);
}